// Round 1
// baseline (6011.098 us; speedup 1.0000x reference)
//
#include <hip/hip_runtime.h>

#define B_   8
#define D_   256
#define T_   4096
#define NQ_  8
#define K_   1024

#define ROWS  32            // rows per block
#define CHUNK 256           // codes per chunk
#define DC    16            // d per staging chunk
#define RSTR  36            // resT row stride (pad: 36%32=4 -> <=8-way on rare d-fast ops; 16B aligned)
#define NBLK  ((B_ * T_) / ROWS)   // 1024

#define IDX_OFF  ((size_t)B_ * T_ * D_)             // 8388608
#define LOSS_OFF (IDX_OFF + (size_t)NQ_ * B_ * T_)  // 8650752

__device__ __forceinline__ bool better(float a, int ai, float b, int bi) {
  return (a < b) || (a == b && ai < bi);   // tie -> smaller index (numpy argmin rule)
}

__global__ __launch_bounds__(256, 2)
void rvq_main(const float* __restrict__ x, const float* __restrict__ cb,
              float* __restrict__ out, double* __restrict__ lossbuf) {
  // LDS: 36864 + 16384 + 1024 + 256 + 1024 = 55552 B  (< 64 KB -> 2 blocks/CU)
  __shared__ __align__(16) float resT[D_ * RSTR];   // [d][r], f32 mirror of exact residual
  __shared__ __align__(16) float Bt[DC * CHUNK];    // [dd][c] staged codes
  __shared__ float cnormAcc[CHUNK];                 // per-chunk ||c||^2 (f32)
  __shared__ int   t2i[ROWS][2];                    // per-row top-2 candidate indices
  __shared__ int   hist[NQ_][ROWS];                 // chosen code per stage per row

  const int tid = threadIdx.x;
  const int bid = blockIdx.x;
  const int b   = bid >> 7;            // 128 blocks per batch elem (4096/32)
  const int t0  = (bid & 127) << 5;
  const float* __restrict__ xb = x + (size_t)b * D_ * T_;

  // ---- init: resT[d][r] = x[b][d][t0+r]  (coalesced along t) ----
  {
    const int r = tid & 31, dg = tid >> 5;   // dg 0..7
    for (int i = 0; i < 32; ++i) {
      const int d = dg * 32 + i;
      resT[d * RSTR + r] = xb[(size_t)d * T_ + t0 + r];
    }
  }

  const int ty = tid >> 6;   // wave id 0..3  (wave handles rows ty*8 .. ty*8+7)
  const int tx = tid & 63;

  for (int s = 0; s < NQ_; ++s) {
    const float* __restrict__ cbs = cb + (size_t)s * K_ * D_;

    // running per-lane top-2 for this wave's 8 rows
    float v1[8], v2[8]; int i1[8], i2[8];
#pragma unroll
    for (int r = 0; r < 8; ++r) { v1[r] = 1e30f; v2[r] = 1e30f; i1[r] = 0; i2[r] = 0; }

    // ================= fast pass: fused fp32 GEMM + top-2 =================
    for (int ch = 0; ch < K_ / CHUNK; ++ch) {
      __syncthreads();
      cnormAcc[tid] = 0.f;
      float acc[8][4];
#pragma unroll
      for (int r = 0; r < 8; ++r)
#pragma unroll
        for (int c = 0; c < 4; ++c) acc[r][c] = 0.f;

      for (int dc = 0; dc < D_ / DC; ++dc) {
        __syncthreads();
        // stage Bt[dd][c]: 256 codes x 16 d, 64B-per-code coalesced reads
        {
          const int cl = tid >> 2, dq = tid & 3;
#pragma unroll
          for (int rr = 0; rr < 4; ++rr) {
            const int c_local = rr * 64 + cl;
            const float4 v = *(const float4*)(cbs + (size_t)(ch * CHUNK + c_local) * D_ + dc * DC + dq * 4);
            Bt[(dq * 4 + 0) * CHUNK + c_local] = v.x;
            Bt[(dq * 4 + 1) * CHUNK + c_local] = v.y;
            Bt[(dq * 4 + 2) * CHUNK + c_local] = v.z;
            Bt[(dq * 4 + 3) * CHUNK + c_local] = v.w;
            atomicAdd(&cnormAcc[c_local], v.x * v.x + v.y * v.y + v.z * v.z + v.w * v.w);
          }
        }
        __syncthreads();
#pragma unroll
        for (int dd = 0; dd < DC; ++dd) {
          const int d = dc * DC + dd;
          const float4 a0 = *(const float4*)(resT + d * RSTR + ty * 8);      // broadcast
          const float4 a1 = *(const float4*)(resT + d * RSTR + ty * 8 + 4);  // broadcast
          const float4 bb = *(const float4*)(Bt + dd * CHUNK + tx * 4);
          const float av[8] = {a0.x, a0.y, a0.z, a0.w, a1.x, a1.y, a1.z, a1.w};
          const float bv[4] = {bb.x, bb.y, bb.z, bb.w};
#pragma unroll
          for (int r = 0; r < 8; ++r)
#pragma unroll
            for (int c = 0; c < 4; ++c)
              acc[r][c] = fmaf(av[r], bv[c], acc[r][c]);
        }
      }
      // fold into running top-2 (score = ||c||^2 - 2<r,c>, monotone with distance)
      const float4 cn4 = *(const float4*)(cnormAcc + tx * 4);
      const float cna[4] = {cn4.x, cn4.y, cn4.z, cn4.w};
#pragma unroll
      for (int c = 0; c < 4; ++c) {
        const int code = ch * CHUNK + tx * 4 + c;
#pragma unroll
        for (int r = 0; r < 8; ++r) {
          const float sc = cna[c] - 2.0f * acc[r][c];
          if (sc < v1[r])      { v2[r] = v1[r]; i2[r] = i1[r]; v1[r] = sc; i1[r] = code; }
          else if (sc < v2[r]) { v2[r] = sc; i2[r] = code; }
        }
      }
    }
    // butterfly merge top-2 across the 64 lanes (codes dimension)
#pragma unroll
    for (int m = 1; m <= 32; m <<= 1) {
#pragma unroll
      for (int r = 0; r < 8; ++r) {
        const float w1 = __shfl_xor(v1[r], m);
        const int   j1 = __shfl_xor(i1[r], m);
        const float w2 = __shfl_xor(v2[r], m);
        const int   j2 = __shfl_xor(i2[r], m);
        if (better(w1, j1, v1[r], i1[r])) {
          const float ov = v1[r]; const int oi = i1[r];
          v1[r] = w1; i1[r] = j1;
          if (better(ov, oi, w2, j2)) { v2[r] = ov; i2[r] = oi; }
          else                        { v2[r] = w2; i2[r] = j2; }
        } else if (better(w1, j1, v2[r], i2[r])) {
          v2[r] = w1; i2[r] = j1;
        }
      }
    }
    if (tx == 0) {
#pragma unroll
      for (int r = 0; r < 8; ++r) { t2i[ty * 8 + r][0] = i1[r]; t2i[ty * 8 + r][1] = i2[r]; }
    }
    __syncthreads();

    // ========== phase 3: f64 re-eval of top-2, residual update, loss ==========
    double lossW = 0.0;
    for (int rg = 0; rg < 8; ++rg) {
      const int r = ty * 8 + rg;
      const int bi1 = t2i[r][0], bi2 = t2i[r][1];
      double res64[4]; float xv[4], c1f[4], c2f[4];
      // exact residual: f64(x) - sum of chosen codes (f64), lane tx covers d = tx+64j
#pragma unroll
      for (int j = 0; j < 4; ++j) {
        const int d = tx + 64 * j;
        xv[j] = xb[(size_t)d * T_ + t0 + r];
        res64[j] = (double)xv[j];
      }
      for (int q = 0; q < s; ++q) {
        const float* crow = cb + (size_t)q * K_ * D_ + (size_t)hist[q][r] * D_;
#pragma unroll
        for (int j = 0; j < 4; ++j) res64[j] -= (double)crow[tx + 64 * j];
      }
      const float* c1p = cbs + (size_t)bi1 * D_;
      const float* c2p = cbs + (size_t)bi2 * D_;
      double d1 = 0.0, d2 = 0.0;
#pragma unroll
      for (int j = 0; j < 4; ++j) {
        c1f[j] = c1p[tx + 64 * j];
        c2f[j] = c2p[tx + 64 * j];
        const double u = res64[j] - (double)c1f[j]; d1 += u * u;
        const double w = res64[j] - (double)c2f[j]; d2 += w * w;
      }
#pragma unroll
      for (int m = 1; m <= 32; m <<= 1) { d1 += __shfl_xor(d1, m); d2 += __shfl_xor(d2, m); }
      const bool take1 = (d1 < d2) || (d1 == d2 && bi1 < bi2);
      const int win = take1 ? bi1 : bi2;
      const double dmin = take1 ? d1 : d2;
      if (tx == 0) {
        hist[s][r] = win;
        out[IDX_OFF + (size_t)s * (B_ * T_) + (size_t)b * T_ + t0 + r] = (float)win;
        lossW += dmin;
      }
#pragma unroll
      for (int j = 0; j < 4; ++j) {
        const float cw = take1 ? c1f[j] : c2f[j];
        const double nr = res64[j] - (double)cw;
        const int d = tx + 64 * j;
        if (s < NQ_ - 1) {
          resT[d * RSTR + r] = (float)nr;               // f32 mirror for next fast pass
        } else {
          // quantized_out = x - final residual  (== sum of chosen codes)
          out[((size_t)b * T_ + t0 + r) * D_ + d] = (float)((double)xv[j] - nr);
        }
      }
    }
    if (tx == 0) atomicAdd(&lossbuf[s], lossW);
    __syncthreads();
  }
}

__global__ void rvq_loss(const double* __restrict__ lossbuf, float* __restrict__ out) {
  const int s = threadIdx.x;
  if (s < NQ_) {
    // loss = mean((sg(q)-res)^2) + mean((q-sg(res))^2) = 2 * mean(new_res^2)
    out[LOSS_OFF + s] = (float)(2.0 * lossbuf[s] / (double)((size_t)B_ * T_ * D_));
  }
}

extern "C" void kernel_launch(void* const* d_in, const int* in_sizes, int n_in,
                              void* d_out, int out_size, void* d_ws, size_t ws_size,
                              hipStream_t stream) {
  const float* x  = (const float*)d_in[0];   // [B, D, T] f32
  const float* cb = (const float*)d_in[1];   // [NQ, K, D] f32
  float* out = (float*)d_out;                // [B*T*D] quantized | [NQ*B*T] indices | [NQ] losses
  double* lossbuf = (double*)d_ws;           // 8 doubles of scratch

  hipMemsetAsync(d_ws, 0, NQ_ * sizeof(double), stream);
  rvq_main<<<NBLK, 256, 0, stream>>>(x, cb, out, lossbuf);
  rvq_loss<<<1, 64, 0, stream>>>(lossbuf, out);
}

// Round 2
// 1991.825 us; speedup vs baseline: 3.0179x; 3.0179x over previous
//
#include <hip/hip_runtime.h>

#define B_   8
#define D_   256
#define T_   4096
#define NQ_  8
#define K_   1024

#define IDX_OFF  ((size_t)B_ * T_ * D_)             // 8388608
#define LOSS_OFF (IDX_OFF + (size_t)NQ_ * B_ * T_)  // 8650752

// ---- workspace layout (bytes) ----
#define RES_OFF  0ull                      // uint res_pack[32768][256] : packed bf16 hi|lo residual (32 MB)
#define CBH_OFF  33554432ull               // bf16-hi codebook, staging order + swizzle (4 MB)
#define CBL_OFF  37748736ull               // bf16-lo codebook (4 MB)
#define CN_OFF   41943040ull               // float cnorm[NQ*K] (32 KB)
#define LB_OFF   41975808ull               // double lossbuf[NQ]

typedef __attribute__((ext_vector_type(8)))  short  short8;   // 8 bf16 = 4 VGPR (MFMA A/B frag)
typedef __attribute__((ext_vector_type(16))) float  f32x16;   // MFMA C/D

__device__ __forceinline__ uint bf16_rne(float f) {
  uint u = __builtin_bit_cast(uint, f);
  return ((u + 0x7fffu + ((u >> 16) & 1u)) >> 16) & 0xffffu;
}
__device__ __forceinline__ uint pack_hilo(float f) {
  uint hb = bf16_rne(f);
  float hf = __builtin_bit_cast(float, hb << 16);
  uint lb = bf16_rne(f - hf);
  return (hb << 16) | lb;
}

__device__ __forceinline__ f32x16 mfma_bf16(short8 a, short8 b, f32x16 c) {
  return __builtin_amdgcn_mfma_f32_32x32x16_bf16(a, b, c, 0, 0, 0);
}

__device__ __forceinline__ void cp1024(const uint* __restrict__ g, uint* l, int lane) {
#if __has_builtin(__builtin_amdgcn_global_load_lds)
  __builtin_amdgcn_global_load_lds(
      (const __attribute__((address_space(1))) uint*)(g + lane * 4),
      (__attribute__((address_space(3))) uint*)(l), 16, 0, 0);
#else
  ((uint4*)l)[lane] = ((const uint4*)g)[lane];
#endif
}

// ---- prep 1: convert codebooks to bf16 hi/lo in staging order (+bank swizzle) + cnorm ----
__global__ void prep_cb(const float* __restrict__ cb, uint* __restrict__ cbh,
                        uint* __restrict__ cbl, float* __restrict__ cnorm) {
  const int tid  = threadIdx.x;
  const int half = tid >> 5;              // 0..7 : half-wave per code
  const int l5   = tid & 31;
  const int code = blockIdx.x * 8 + half; // 0..8191
  const int s  = code >> 10, ci = code & 1023;
  const int ct = ci >> 5,   cl = ci & 31;
  const float* row = cb + (size_t)code * D_;
  const int kq = l5 >> 3, gq = l5 & 7;    // k-quarter (64k), granule (8k) within quarter
  const int k0 = l5 * 8;
  float4 f0 = *(const float4*)(row + k0);
  float4 f1 = *(const float4*)(row + k0 + 4);
  float v[8] = {f0.x, f0.y, f0.z, f0.w, f1.x, f1.y, f1.z, f1.w};
  uint hi[8], lo[8];
  double nrm = 0.0;
#pragma unroll
  for (int j = 0; j < 8; ++j) {
    nrm += (double)v[j] * (double)v[j];
    uint hb = bf16_rne(v[j]);
    float hf = __builtin_bit_cast(float, hb << 16);
    hi[j] = hb; lo[j] = bf16_rne(v[j] - hf);
  }
  uint4 ph = make_uint4(hi[0]|(hi[1]<<16), hi[2]|(hi[3]<<16), hi[4]|(hi[5]<<16), hi[6]|(hi[7]<<16));
  uint4 pl = make_uint4(lo[0]|(lo[1]<<16), lo[2]|(lo[3]<<16), lo[4]|(lo[5]<<16), lo[6]|(lo[7]<<16));
  // chunk = (s, ct, kq) : 4 KB = 1024 uints; within: code row cl*32 uints, granule XOR-swizzled
  size_t off = ((size_t)((s * 32 + ct) * 4 + kq) << 10) + (size_t)cl * 32 + (uint)((gq ^ (cl & 7)) << 2);
  *(uint4*)(cbh + off) = ph;
  *(uint4*)(cbl + off) = pl;
#pragma unroll
  for (int m = 1; m <= 16; m <<= 1) nrm += __shfl_xor(nrm, m);
  if (l5 == 0) cnorm[code] = (float)nrm;
}

// ---- prep 2: res_pack[row][d] = packed bf16 hi/lo of x (transposed) ----
__global__ void prep_x(const float* __restrict__ x, uint* __restrict__ resp) {
  __shared__ float tile[64][65];
  const int bidx = blockIdx.x;                 // 8 b * 4 dchunk * 64 tchunk
  const int b = bidx >> 8, dc = (bidx >> 6) & 3, tc = bidx & 63;
  const int d0 = dc * 64, t0 = tc * 64;
  const int tid = threadIdx.x;
  {
    const int tt = tid & 63, dg = tid >> 6;
    for (int i = 0; i < 16; ++i) {
      const int d = dg * 16 + i;
      tile[d][tt] = x[((size_t)(b * D_ + d0 + d)) * T_ + t0 + tt];
    }
  }
  __syncthreads();
  {
    const int dw = tid & 63, tg = tid >> 6;
    for (int i = 0; i < 16; ++i) {
      const int t = tg * 16 + i;
      const size_t rowg = (size_t)b * T_ + t0 + t;
      resp[rowg * D_ + d0 + dw] = pack_hilo(tile[dw][t]);
    }
  }
}

// ---- main: per stage [a-frag load | 3-split MFMA top-2 | f64 re-eval + residual update] ----
__global__ __launch_bounds__(256, 2)
void rvq_main(const float* __restrict__ x, const float* __restrict__ cb,
              float* __restrict__ out, uint* __restrict__ resp,
              const uint* __restrict__ cbh, const uint* __restrict__ cbl,
              const float* __restrict__ cnorm, double* __restrict__ lossbuf) {
  __shared__ __align__(16) uint Bbuf[2][2][2][1024];  // [stream][dbuf][hi/lo][4KB]
  __shared__ float t2v[64][2][2];
  __shared__ int   t2i[64][2][2];
  __shared__ int   hist[NQ_][64];

  const int tid  = threadIdx.x;
  const int w    = tid >> 6;      // wave 0..3
  const int l    = tid & 63;
  const int n5   = l & 31;        // MFMA col (code) / A row (m)
  const int h    = l >> 5;
  const int st   = w & 1;         // code stream: 0 -> codes 0..511, 1 -> 512..1023
  const int tile = w >> 1;        // row tile 0/1 (rows tile*32 .. +31)
  const int hl   = w >> 1;        // staging duty: hi(0)/lo(1) buffers of stream st
  const int bid  = blockIdx.x;
  const int b    = bid >> 6;
  const int t0   = (bid & 63) * 64;

  const size_t rowA_g = (size_t)bid * 64 + tile * 32 + n5;

  for (int s = 0; s < NQ_; ++s) {
    // ===== A fragments from res_pack (registers, whole K) =====
    short8 a_hi[16], a_lo[16];
#pragma unroll
    for (int stp = 0; stp < 16; ++stp) {
      const uint* p = resp + rowA_g * D_ + stp * 16 + h * 8;
      uint4 pA = *(const uint4*)p;
      uint4 pB = *(const uint4*)(p + 4);
      uint4 H = make_uint4((pA.x>>16)|(pA.y&0xffff0000u), (pA.z>>16)|(pA.w&0xffff0000u),
                           (pB.x>>16)|(pB.y&0xffff0000u), (pB.z>>16)|(pB.w&0xffff0000u));
      uint4 L = make_uint4((pA.x&0xffffu)|(pA.y<<16), (pA.z&0xffffu)|(pA.w<<16),
                           (pB.x&0xffffu)|(pB.y<<16), (pB.z&0xffffu)|(pB.w<<16));
      a_hi[stp] = __builtin_bit_cast(short8, H);
      a_lo[stp] = __builtin_bit_cast(short8, L);
    }

    // ===== fused GEMM + per-stream top-2 =====
    float v1[16], v2[16]; uint ip[16];
#pragma unroll
    for (int rr = 0; rr < 16; ++rr) { v1[rr] = 3e38f; v2[rr] = 3e38f; ip[rr] = 0; }
    f32x16 acc;

    const uint* cbsrc = (hl ? cbl : cbh);
    const size_t sbase = (size_t)s * 131072;   // uints per stage (32 ct * 4 kq * 1024)

    // stage chunk 0
    {
      const uint* src = cbsrc + sbase + ((size_t)((st * 16 + 0) * 4 + 0) << 10);
      uint* dst = &Bbuf[st][0][hl][0];
      for (int q = 0; q < 4; ++q) cp1024(src + (q << 8), dst + (q << 8), l);
    }
    __syncthreads();

    for (int step = 0; step < 64; ++step) {
      if (step < 63) {
        const int ns = step + 1;
        const uint* src = cbsrc + sbase + ((size_t)((st * 16 + (ns >> 2)) * 4 + (ns & 3)) << 10);
        uint* dst = &Bbuf[st][ns & 1][hl][0];
        for (int q = 0; q < 4; ++q) cp1024(src + (q << 8), dst + (q << 8), l);
      }
      const int cur = step & 1, ctl = step >> 2, kq = step & 3;
      const uint* bh = &Bbuf[st][cur][0][0];
      const uint* bl = &Bbuf[st][cur][1][0];
      if (kq == 0) {
#pragma unroll
        for (int rr = 0; rr < 16; ++rr) acc[rr] = 0.0f;
      }
#pragma unroll
      for (int s2 = 0; s2 < 4; ++s2) {
        const int off = n5 * 32 + (((s2 * 2 + h) ^ (n5 & 7)) << 2);
        short8 bhf = __builtin_bit_cast(short8, *(const uint4*)(bh + off));
        short8 blf = __builtin_bit_cast(short8, *(const uint4*)(bl + off));
        const int ks = kq * 4 + s2;
        acc = mfma_bf16(a_hi[ks], bhf, acc);   // Ah*Bh
        acc = mfma_bf16(a_lo[ks], bhf, acc);   // Al*Bh
        acc = mfma_bf16(a_hi[ks], blf, acc);   // Ah*Bl
      }
      if (kq == 3) {
        const int code = st * 512 + ctl * 32 + n5;
        const float cn = cnorm[s * K_ + code];
#pragma unroll
        for (int rr = 0; rr < 16; ++rr) {
          const float sc = cn - 2.0f * acc[rr];
          if (sc < v1[rr])      { v2[rr] = v1[rr]; v1[rr] = sc; ip[rr] = ((ip[rr] & 0xffffu) << 16) | (uint)code; }
          else if (sc < v2[rr]) { v2[rr] = sc; ip[rr] = (ip[rr] & 0xffffu) | ((uint)code << 16); }
        }
      }
      __syncthreads();
    }

    // cross-lane top-2 merge (cols live in lane&31; bit5 = row offset, keep masks <= 16)
#pragma unroll
    for (int m = 1; m <= 16; m <<= 1) {
#pragma unroll
      for (int rr = 0; rr < 16; ++rr) {
        float ov1 = __shfl_xor(v1[rr], m);
        float ov2 = __shfl_xor(v2[rr], m);
        uint  oip = (uint)__shfl_xor((int)ip[rr], m);
        if (ov1 < v1[rr]) {
          if (v1[rr] < ov2) { v2[rr] = v1[rr]; ip[rr] = (oip & 0xffffu) | ((ip[rr] & 0xffffu) << 16); }
          else              { v2[rr] = ov2;    ip[rr] = oip; }
          v1[rr] = ov1;
        } else if (ov1 < v2[rr]) {
          v2[rr] = ov1; ip[rr] = (ip[rr] & 0xffffu) | ((oip & 0xffffu) << 16);
        }
      }
    }
    if (n5 == 0) {
#pragma unroll
      for (int rr = 0; rr < 16; ++rr) {
        const int row = tile * 32 + (rr & 3) + 8 * (rr >> 2) + 4 * h;  // measured C/D layout (m74/m101)
        t2v[row][st][0] = v1[rr]; t2v[row][st][1] = v2[rr];
        t2i[row][st][0] = (int)(ip[rr] & 0xffffu); t2i[row][st][1] = (int)(ip[rr] >> 16);
      }
    }
    __syncthreads();

    // ===== exact f64 re-eval of top-2-of-4, residual update, loss =====
    double lossW = 0.0;
    const int r0 = tile * 32 + st * 16;
    for (int it = 0; it < 8; ++it) {
      const int rl = r0 + it * 2 + h;
      const int t  = t0 + rl;
      const size_t rowg = (size_t)bid * 64 + rl;
      const float va1 = t2v[rl][0][0], va2 = t2v[rl][0][1];
      const float vb1 = t2v[rl][1][0], vb2 = t2v[rl][1][1];
      const int   ia1 = t2i[rl][0][0], ia2 = t2i[rl][0][1];
      const int   ib1 = t2i[rl][1][0], ib2 = t2i[rl][1][1];
      int bi1, bi2;
      if (va1 <= vb1) { bi1 = ia1; bi2 = (va2 <= vb1) ? ia2 : ib1; }
      else            { bi1 = ib1; bi2 = (vb2 <= va1) ? ib2 : ia1; }

      const int d0i = n5 * 8;
      double res64[8]; float xv[8];
#pragma unroll
      for (int j = 0; j < 8; ++j) {
        xv[j] = x[((size_t)(b * D_ + d0i + j)) * T_ + t];
        res64[j] = (double)xv[j];
      }
      for (int q = 0; q < s; ++q) {
        const float* cr = cb + ((size_t)(q * K_ + hist[q][rl])) * D_ + d0i;
        float4 c0 = *(const float4*)cr, c1 = *(const float4*)(cr + 4);
        const float cf[8] = {c0.x, c0.y, c0.z, c0.w, c1.x, c1.y, c1.z, c1.w};
#pragma unroll
        for (int j = 0; j < 8; ++j) res64[j] -= (double)cf[j];
      }
      const float* c1p = cb + ((size_t)(s * K_ + bi1)) * D_ + d0i;
      const float* c2p = cb + ((size_t)(s * K_ + bi2)) * D_ + d0i;
      float4 a0 = *(const float4*)c1p, a1 = *(const float4*)(c1p + 4);
      float4 b0 = *(const float4*)c2p, b1 = *(const float4*)(c2p + 4);
      const float c1f[8] = {a0.x, a0.y, a0.z, a0.w, a1.x, a1.y, a1.z, a1.w};
      const float c2f[8] = {b0.x, b0.y, b0.z, b0.w, b1.x, b1.y, b1.z, b1.w};
      double d1 = 0.0, d2 = 0.0;
#pragma unroll
      for (int j = 0; j < 8; ++j) {
        const double u = res64[j] - (double)c1f[j]; d1 += u * u;
        const double vv = res64[j] - (double)c2f[j]; d2 += vv * vv;
      }
#pragma unroll
      for (int m = 1; m <= 16; m <<= 1) { d1 += __shfl_xor(d1, m); d2 += __shfl_xor(d2, m); }
      const bool take1 = (d1 < d2) || (d1 == d2 && bi1 < bi2);
      const int win = take1 ? bi1 : bi2;
      const double dwin = take1 ? d1 : d2;
      if (s < NQ_ - 1) {
        uint pk[8];
#pragma unroll
        for (int j = 0; j < 8; ++j)
          pk[j] = pack_hilo((float)(res64[j] - (double)(take1 ? c1f[j] : c2f[j])));
        uint* dst = resp + rowg * D_ + d0i;
        *(uint4*)dst       = make_uint4(pk[0], pk[1], pk[2], pk[3]);
        *(uint4*)(dst + 4) = make_uint4(pk[4], pk[5], pk[6], pk[7]);
      } else {
        float* od = out + ((size_t)(b * T_ + t)) * D_ + d0i;
#pragma unroll
        for (int j = 0; j < 8; ++j)
          od[j] = (float)((double)xv[j] - (res64[j] - (double)(take1 ? c1f[j] : c2f[j])));
      }
      if (n5 == 0) {
        hist[s][rl] = win;
        out[IDX_OFF + (size_t)s * (B_ * T_) + (size_t)b * T_ + t] = (float)win;
        lossW += dwin;
      }
    }
    if (n5 == 0) atomicAdd(&lossbuf[s], lossW);
    __syncthreads();
  }
}

__global__ void rvq_loss(const double* __restrict__ lossbuf, float* __restrict__ out) {
  const int s = threadIdx.x;
  if (s < NQ_) out[LOSS_OFF + s] = (float)(2.0 * lossbuf[s] / (double)((size_t)B_ * T_ * D_));
}

extern "C" void kernel_launch(void* const* d_in, const int* in_sizes, int n_in,
                              void* d_out, int out_size, void* d_ws, size_t ws_size,
                              hipStream_t stream) {
  const float* x  = (const float*)d_in[0];
  const float* cb = (const float*)d_in[1];
  float* out = (float*)d_out;
  char* ws = (char*)d_ws;
  uint*   resp = (uint*)(ws + RES_OFF);
  uint*   cbh  = (uint*)(ws + CBH_OFF);
  uint*   cbl  = (uint*)(ws + CBL_OFF);
  float*  cn   = (float*)(ws + CN_OFF);
  double* lb   = (double*)(ws + LB_OFF);

  hipMemsetAsync(ws + LB_OFF, 0, NQ_ * sizeof(double), stream);
  prep_cb<<<NQ_ * K_ / 8, 256, 0, stream>>>(cb, cbh, cbl, cn);
  prep_x<<<2048, 256, 0, stream>>>(x, resp);
  rvq_main<<<512, 256, 0, stream>>>(x, cb, out, resp, cbh, cbl, cn, lb);
  rvq_loss<<<1, 64, 0, stream>>>(lb, out);
}